// Round 2
// 274.571 us; speedup vs baseline: 1.0311x; 1.0311x over previous
//
#include <hip/hip_runtime.h>
#include <math.h>

// Problem constants: B=8, C=64, H=W=256, M1=M2=16.
#define NIMG 512          // B*C
#define HW   65536        // 256*256
// Workspace (floats): xf_re[131072] xf_im[131072]

// ---------------- Stage A ----------------
// One block per input image (b,i). Radix-4 over h, then over w.
// Phase 1 (thread t = column w): C[u,t] = sum_h x[h,t] e^{-2pi i u h/256}
// Phase 2 (thread t -> u=t>>4, v=t&15): Xf[u,v] = sum_w C[u,w] e^{-2pi i v w/256}
__global__ __launch_bounds__(256, 2)
void stageA(const float* __restrict__ x,
            float* __restrict__ xf_re, float* __restrict__ xf_im) {
    __shared__ __attribute__((aligned(16))) float tw[2048];   // [n=64][k=16][2], 8 KB
    __shared__ __attribute__((aligned(16))) float cbuf[8192]; // [u=16][w=256][2], 32 KB
    const int tid = threadIdx.x;
    const int img = blockIdx.x;

    // Build radix-4 twiddle table in LDS (no global round-trip).
    #pragma unroll
    for (int j = 0; j < 4; ++j) {
        int idx = (tid << 2) | j;           // 0..1023
        int n = idx >> 4, k = idx & 15;
        float s, c;
        sincospif(((k * n) & 255) * (1.0f / 128.0f), &s, &c);  // 2*pi*k*n/256
        tw[idx * 2]     = c;
        tw[idx * 2 + 1] = s;
    }
    __syncthreads();

    const float* xp = x + (size_t)img * HW + tid;
    float cr[16], ci[16];
    #pragma unroll
    for (int u = 0; u < 16; ++u) { cr[u] = 0.0f; ci[u] = 0.0f; }

    const float4* tw4 = (const float4*)tw;
    // 16 independent loads per group -> 4 KB/wave in flight.
    #pragma unroll 1
    for (int hb = 0; hb < 64; hb += 4) {
        float av[4], bv[4], cv[4], dv[4];
        #pragma unroll
        for (int j = 0; j < 4; ++j) {
            av[j] = xp[(hb + j) * 256];
            bv[j] = xp[(hb + j + 64) * 256];
            cv[j] = xp[(hb + j + 128) * 256];
            dv[j] = xp[(hb + j + 192) * 256];
        }
        #pragma unroll
        for (int j = 0; j < 4; ++j) {
            float p = av[j] + cv[j], m = av[j] - cv[j];
            float q = bv[j] + dv[j], r = bv[j] - dv[j];
            float s0 = p + q, s2 = p - q;
            #pragma unroll
            for (int qq = 0; qq < 8; ++qq) {
                float4 e = tw4[(hb + j) * 8 + qq];   // uniform -> LDS broadcast b128
                float se = (qq & 1) ? s2 : s0;       // compile-time select after unroll
                float si = (qq & 1) ? r : -r;
                cr[2*qq]     += se * e.x;
                ci[2*qq]     -= se * e.y;
                cr[2*qq + 1] += m  * e.z + si * e.w;
                ci[2*qq + 1] += si * e.z - m  * e.w;
            }
        }
    }

    float2* cb = (float2*)cbuf;               // [u*256 + w]
    #pragma unroll
    for (int u = 0; u < 16; ++u)
        cb[u * 256 + tid] = make_float2(cr[u], ci[u]);
    __syncthreads();

    const int u = tid >> 4, v = tid & 15;
    const bool odd = (v & 1) != 0;
    const float t = (v & 2) ? -1.0f : 1.0f;
    const float2* twc = (const float2*)tw;
    float xr = 0.0f, xi = 0.0f;
    #pragma unroll 2
    for (int wb = 0; wb < 64; ++wb) {
        float2 Ca = cb[u * 256 + wb];
        float2 Cb = cb[u * 256 + wb + 64];
        float2 Cc = cb[u * 256 + wb + 128];
        float2 Cd = cb[u * 256 + wb + 192];
        float pr = Ca.x + Cc.x, pi_ = Ca.y + Cc.y;
        float mr = Ca.x - Cc.x, mi  = Ca.y - Cc.y;
        float qr = Cb.x + Cd.x, qi  = Cb.y + Cd.y;
        float rr = Cb.x - Cd.x, ri  = Cb.y - Cd.y;
        float X1 = odd ? mr : pr;
        float X2 = odd ? ri : qr;
        float Y1 = odd ? mi : pi_;
        float Y2 = odd ? -rr : qi;
        float sr_ = X1 + t * X2;
        float si_ = Y1 + t * Y2;
        float2 e = twc[wb * 16 + v];
        xr += sr_ * e.x + si_ * e.y;
        xi += si_ * e.x - sr_ * e.y;
    }
    xf_re[img * 256 + tid] = xr;
    xf_im[img * 256 + tid] = xi;
}

// ---------------- Stage BC ----------------
// One block per output image (b,o). Stage B (channel mix) in registers feeding
// the 16x16 -> 256x256 inverse transform. Kernel boundary = A->BC barrier.
__global__ __launch_bounds__(256, 2)
void stageBC(const float* __restrict__ wr, const float* __restrict__ wi,
             const float* __restrict__ xf_re, const float* __restrict__ xf_im,
             float* __restrict__ out) {
    __shared__ __attribute__((aligned(16))) float tw[2048];  // 8 KB
    __shared__ __attribute__((aligned(16))) float sl[512];   // [u][v][2], pre-scaled
    const int tid = threadIdx.x;

    #pragma unroll
    for (int j = 0; j < 4; ++j) {
        int idx = (tid << 2) | j;
        int n = idx >> 4, k = idx & 15;
        float s, c;
        sincospif(((k * n) & 255) * (1.0f / 128.0f), &s, &c);
        tw[idx * 2]     = c;
        tw[idx * 2 + 1] = s;
    }

    // XCD-bijective swizzle: blocks with g%8==x (same XCD) share an 8-wide o-panel,
    // so each XCD's L2 holds ~1 MB of w instead of streaming all 8 MB.
    const int g = blockIdx.x;
    const int o = ((g & 7) << 3) | ((g >> 6) & 7);
    const int b = (g >> 3) & 7;

    // Stage B: channel mix for this (b,o), one mode (u,v)=tid per thread.
    float sr = 0.0f, si = 0.0f;
    #pragma unroll 8
    for (int i = 0; i < 64; ++i) {
        float wre = wr[((i * 64 + o) << 8) + tid];
        float wim = wi[((i * 64 + o) << 8) + tid];
        float xr  = xf_re[((b * 64 + i) << 8) + tid];
        float xi  = xf_im[((b * 64 + i) << 8) + tid];
        sr += xr * wre - xi * wim;
        si += xr * wim + xi * wre;
    }

    {
        int v = tid & 15;
        float scale = (v == 0 ? 1.0f : 2.0f) * (1.0f / 65536.0f);
        sl[tid * 2]     = sr * scale;
        sl[tid * 2 + 1] = si * scale;
    }
    __syncthreads();

    float tr[16], ti[16];
    #pragma unroll
    for (int u = 0; u < 16; ++u) { tr[u] = 0.0f; ti[u] = 0.0f; }

    float bs, bc;
    sincospif(tid * (1.0f / 128.0f), &bs, &bc);   // e^{+2pi i w/256}
    float ec = 1.0f, es = 0.0f;
    for (int v = 0; v < 16; ++v) {
        #pragma unroll
        for (int u = 0; u < 16; ++u) {
            float a  = sl[(u * 16 + v) * 2];       // uniform -> broadcast
            float b2 = sl[(u * 16 + v) * 2 + 1];
            tr[u] += a * ec - b2 * es;
            ti[u] += a * es + b2 * ec;
        }
        float nc = ec * bc - es * bs;
        float ns = ec * bs + es * bc;
        ec = nc; es = ns;
    }

    float* op = out + (size_t)(b * 64 + o) * HW + tid;
    const float4* tw4 = (const float4*)tw;
    #pragma unroll 2
    for (int hb = 0; hb < 64; ++hb) {
        float o0 = 0.f, o1 = 0.f, o2 = 0.f, o3 = 0.f;
        #pragma unroll
        for (int qq = 0; qq < 8; ++qq) {          // u = 2qq, 2qq+1
            float4 e = tw4[hb * 8 + qq];          // uniform broadcast
            float pre = tr[2*qq]   * e.x - ti[2*qq]   * e.y;
            float pro = tr[2*qq+1] * e.z - ti[2*qq+1] * e.w;
            float pio = tr[2*qq+1] * e.w + ti[2*qq+1] * e.z;
            o0 += pre + pro;
            o2 += pre - pro;
            float g1 = pre - pio, g3 = pre + pio;
            if (qq & 1) { o1 -= g1; o3 -= g3; }   // static sign after unroll
            else        { o1 += g1; o3 += g3; }
        }
        op[hb * 256]         = o0;                // 4 coalesced stores
        op[(hb + 64) * 256]  = o1;
        op[(hb + 128) * 256] = o2;
        op[(hb + 192) * 256] = o3;
    }
}

extern "C" void kernel_launch(void* const* d_in, const int* in_sizes, int n_in,
                              void* d_out, int out_size, void* d_ws, size_t ws_size,
                              hipStream_t stream) {
    const float* x  = (const float*)d_in[0];
    const float* wr = (const float*)d_in[1];
    const float* wi = (const float*)d_in[2];
    float* out = (float*)d_out;
    float* ws  = (float*)d_ws;

    float* xf_re = ws;
    float* xf_im = ws + 131072;

    stageA<<<NIMG, 256, 0, stream>>>(x, xf_re, xf_im);
    stageBC<<<NIMG, 256, 0, stream>>>(wr, wi, xf_re, xf_im, out);
}